// Round 1
// baseline (243.527 us; speedup 1.0000x reference)
//
#include <hip/hip_runtime.h>
#include <cstddef>

#define B_  16384
#define F_  2048
#define T_  64
#define C_  32
#define H_  24
#define HH_ 48
#define ROWS 256
#define PAD  33   // 32 + 1: breaks the stride-32 bank alias on the xg tile

// ---------------------------------------------------------------------------
// Kernel A: per (t, row-chunk) block. Gather + 2-stage tiny autoencoder +
// SSE reduction into sse[t] (fp32 atomics, 64 atomics per t total).
// ---------------------------------------------------------------------------
__global__ __launch_bounds__(256) void kitnet_main(
    const float* __restrict__ x, const int* __restrict__ clusters,
    const float* __restrict__ Wt, const float* __restrict__ hb,
    const float* __restrict__ vb, float* __restrict__ sse)
{
    __shared__ __align__(16) float WtL[C_ * H_];   // Wt[t] : [C][H] row-major
    __shared__ float xgL[ROWS * PAD];              // gathered x tile
    __shared__ float hbL[H_];
    __shared__ float vbL[C_];
    __shared__ int   colsL[C_];
    __shared__ int   contigF;
    __shared__ float wsum[4];

    const int tid = threadIdx.x;
    const int t  = blockIdx.x & (T_ - 1);          // t fastest: concurrent blocks stream x
    const int b0 = (blockIdx.x >> 6) * ROWS;

    // --- stage t-local params into LDS ---
    if (tid < C_) colsL[tid] = clusters[t * C_ + tid];
    for (int i = tid; i < C_ * H_; i += 256) WtL[i] = Wt[t * C_ * H_ + i];
    if (tid < H_) hbL[tid] = hb[t * H_ + tid];
    if (tid < C_) vbL[tid] = vb[t * C_ + tid];
    __syncthreads();
    if (tid == 0) {
        int ok = (colsL[0] & 3) == 0;              // float4 alignment
        for (int c = 1; c < C_; ++c) ok &= (colsL[c] == colsL[0] + c);
        contigF = ok;
    }
    __syncthreads();

    // --- gather x tile into LDS, coalesced ---
    if (contigF) {
        const int col0 = colsL[0];
        #pragma unroll
        for (int p = 0; p < 8; ++p) {
            const int idx = p * 256 + tid;         // 0..2047
            const int row = idx >> 3, c4 = idx & 7;
            const float4 v = *(const float4*)(x + (size_t)(b0 + row) * F_ + col0 + c4 * 4);
            float* dst = &xgL[row * PAD + c4 * 4]; // banks (row+4*c4+j)%32: 2-way, free
            dst[0] = v.x; dst[1] = v.y; dst[2] = v.z; dst[3] = v.w;
        }
    } else {
        #pragma unroll
        for (int p = 0; p < 32; ++p) {
            const int idx = p * 256 + tid;
            const int row = idx >> 5, c = idx & 31;
            xgL[row * PAD + c] = x[(size_t)(b0 + row) * F_ + colsL[c]];
        }
    }
    __syncthreads();

    // --- per-thread: one row b = b0 + tid ---
    float xv[C_];
    #pragma unroll
    for (int c = 0; c < C_; ++c) xv[c] = xgL[tid * PAD + c];  // bank (tid+c)%32: 2-way, free

    float h[H_];
    #pragma unroll
    for (int j = 0; j < H_; ++j) h[j] = hbL[j];

    // stage 1: h = xg @ Wt[t]  (Wt reads are wave-uniform -> LDS broadcast)
    #pragma unroll 4
    for (int c = 0; c < C_; ++c) {
        const float xc = xv[c];
        const float4* wr = (const float4*)&WtL[c * H_];
        #pragma unroll
        for (int j4 = 0; j4 < 6; ++j4) {
            const float4 w = wr[j4];
            h[j4 * 4 + 0] += xc * w.x;
            h[j4 * 4 + 1] += xc * w.y;
            h[j4 * 4 + 2] += xc * w.z;
            h[j4 * 4 + 3] += xc * w.w;
        }
    }

    // stage 2: out_c = h . Wt[t][c] + vb;  err += (out_c - xg_c)^2
    float err = 0.f;
    #pragma unroll 4
    for (int c = 0; c < C_; ++c) {
        const float4* wr = (const float4*)&WtL[c * H_];
        float acc = vbL[c];
        #pragma unroll
        for (int j4 = 0; j4 < 6; ++j4) {
            const float4 w = wr[j4];
            acc += h[j4 * 4 + 0] * w.x + h[j4 * 4 + 1] * w.y
                 + h[j4 * 4 + 2] * w.z + h[j4 * 4 + 3] * w.w;
        }
        const float d = acc - xv[c];
        err += d * d;
    }

    // --- reduce err: wave shuffle -> block -> one atomic ---
    #pragma unroll
    for (int off = 32; off > 0; off >>= 1) err += __shfl_down(err, off, 64);
    if ((tid & 63) == 0) wsum[tid >> 6] = err;
    __syncthreads();
    if (tid == 0) atomicAdd(&sse[t], wsum[0] + wsum[1] + wsum[2] + wsum[3]);
}

// ---------------------------------------------------------------------------
// Kernel B: tails + 2 tiny head matmuls. One wave.
// d_out = [ head_out (64) | tails (64) ]
// ---------------------------------------------------------------------------
__global__ __launch_bounds__(64) void kitnet_head(
    const float* __restrict__ sse, const float* __restrict__ Wh,
    const float* __restrict__ hbh, const float* __restrict__ vbh,
    float* __restrict__ out)
{
    __shared__ float tl[T_];
    __shared__ float hhL[HH_];
    const int tid = threadIdx.x;

    // tails[t] = log(sqrt(mean)) = 0.5*log(sse/(B*C))
    const float tail = 0.5f * logf(sse[tid] * (1.0f / ((float)B_ * (float)C_)));
    tl[tid] = tail;
    out[T_ + tid] = tail;
    __syncthreads();

    if (tid < HH_) {
        float acc = hbh[tid];
        #pragma unroll 8
        for (int t = 0; t < T_; ++t) acc += tl[t] * Wh[t * HH_ + tid];
        hhL[tid] = acc;
    }
    __syncthreads();

    float ho = vbh[tid];
    #pragma unroll 8
    for (int j = 0; j < HH_; ++j) ho += hhL[j] * Wh[tid * HH_ + j];
    out[tid] = ho;
}

extern "C" void kernel_launch(void* const* d_in, const int* in_sizes, int n_in,
                              void* d_out, int out_size, void* d_ws, size_t ws_size,
                              hipStream_t stream)
{
    const float* x        = (const float*)d_in[0];
    const int*   clusters = (const int*)  d_in[1];
    const float* Wt       = (const float*)d_in[2];
    const float* hb       = (const float*)d_in[3];
    const float* vb       = (const float*)d_in[4];
    const float* Wh       = (const float*)d_in[5];
    const float* hbh      = (const float*)d_in[6];
    const float* vbh      = (const float*)d_in[7];
    float* out = (float*)d_out;
    float* sse = (float*)d_ws;   // T_ floats of scratch

    hipMemsetAsync(sse, 0, T_ * sizeof(float), stream);
    kitnet_main<<<dim3(T_ * (B_ / ROWS)), dim3(256), 0, stream>>>(x, clusters, Wt, hb, vb, sse);
    kitnet_head<<<dim3(1), dim3(64), 0, stream>>>(sse, Wh, hbh, vbh, out);
}